// Round 16
// baseline (217.424 us; speedup 1.0000x reference)
//
#include <hip/hip_runtime.h>
#include <hip/hip_fp16.h>

#define N_NODES 50000
#define N_EDGES 800000
#define N_GRAPHS 512
#define VOCAB 10000
#define C 128
#define NBUCK 196            // ceil(50000/256), bucket = dst>>8
#define A_BLOCKS 200         // 4000 edges each
#define EDGES_PER_A (N_EDGES / A_BLOCKS)
#define SE_CAP 8192          // LDS eSrc staging per bucket (mean 4096)
#define NSLICE 8             // channel slices (16 ch each), slice = blockIdx & 7 -> XCD
#define SLICE_H ((size_t)N_NODES*16)   // halves per slice

typedef __attribute__((ext_vector_type(8))) short short8v;
typedef __attribute__((ext_vector_type(4))) float f32x4;

__device__ __forceinline__ unsigned short f2bf(float f){
  unsigned u = __builtin_bit_cast(unsigned, f);
  unsigned r = u + 0x7FFFu + ((u >> 16) & 1u);
  return (unsigned short)(r >> 16);
}
__device__ __forceinline__ float bf2f(unsigned short h){
  unsigned u = ((unsigned)h) << 16;
  return __builtin_bit_cast(float, u);
}
__device__ __forceinline__ float h2f(short s){
  return __half2float(__builtin_bit_cast(__half, (unsigned short)s));
}

// ---------- K1: binCount (200) | gstart (196) | W-prepack (24) | emb->fp16 (64) ----------
__global__ __launch_bounds__(256) void k_pre(const int* __restrict__ dst, int* __restrict__ blockHist,
                      const int* __restrict__ batch, int* __restrict__ gStart,
                      const float* __restrict__ W1, const float* __restrict__ W2,
                      const float* __restrict__ W3, short* __restrict__ Bp,
                      const float* __restrict__ emb, __half* __restrict__ embh){
  __shared__ int h[256];
  int b = blockIdx.x, t = threadIdx.x;
  if (b < A_BLOCKS){
    h[t] = 0; __syncthreads();
    int base = b * EDGES_PER_A;
    for (int i = t; i < EDGES_PER_A; i += 256)
      atomicAdd(&h[dst[base+i] >> 8], 1);
    __syncthreads();
    blockHist[t*A_BLOCKS + b] = h[t];
  } else if (b < A_BLOCKS+NBUCK){
    int i = (b-A_BLOCKS)*256 + t;
    if (i >= N_NODES) return;
    int bb = batch[i];
    int pb = (i==0) ? -1 : batch[i-1];
    for (int g=pb+1; g<=bb; g++) gStart[g] = i;
    if (i == N_NODES-1)
      for (int g=bb+1; g<=N_GRAPHS; g++) gStart[g] = N_NODES;
  } else if (b < A_BLOCKS+NBUCK+24){
    int idx = (b-A_BLOCKS-NBUCK)*256 + t;
    int layer = idx / 2048;
    int r = idx - layer*2048;
    const float* W = (layer==0) ? W1 : (layer==1) ? W2 : W3;
    short* Bh = Bp + (size_t)layer*32768;
    short* Bl = Bh + 16384;
    int lane = r & 63, tile = r >> 6;
    int kt = tile >> 3, ct = tile & 7;
    int q = lane >> 4, c = ct*16 + (lane & 15);
    #pragma unroll
    for (int i=0;i<8;i++){
      int k = kt*32 + q*8 + i;
      float w = W[k*C + c];
      unsigned short hh = f2bf(w);
      unsigned short ll = f2bf(w - bf2f(hh));
      Bh[(size_t)(tile*64 + lane)*8 + i] = (short)hh;
      Bl[(size_t)(tile*64 + lane)*8 + i] = (short)ll;
    }
  } else {
    int idx = (b-A_BLOCKS-NBUCK-24)*256 + t;
    const float2* s = (const float2*)emb;
    __half2* d2 = (__half2*)embh;
    for (int i = idx; i < VOCAB*C/2; i += 64*256)
      d2[i] = __float22half2_rn(s[i]);
  }
}

// ---------- scan A: wave per bucket, prefix over 200 block entries ----------
__global__ __launch_bounds__(64) void k_binScanA(const int* __restrict__ blockHist,
                        int* __restrict__ blockOfs, int* __restrict__ bucketTot){
  int b = blockIdx.x;
  int l = threadIdx.x;
  int carry = 0;
  for (int c = 0; c < 256; c += 64){
    int idx = c + l;
    int v = (idx < A_BLOCKS) ? blockHist[b*A_BLOCKS + idx] : 0;
    int x = v;
    #pragma unroll
    for (int off=1; off<64; off<<=1){
      int y = __shfl_up(x, off);
      if (l >= off) x += y;
    }
    if (idx < A_BLOCKS) blockOfs[b*A_BLOCKS + idx] = carry + x - v;
    carry += __shfl(x, 63);
  }
  if (l == 0) bucketTot[b] = carry;
}

// ---------- binning A2: scatter packed edges ----------
__global__ __launch_bounds__(256) void k_binScatter(const int* __restrict__ src, const int* __restrict__ dst,
                           const int* __restrict__ bucketTot, const int* __restrict__ blockOfs,
                           unsigned* __restrict__ binned){
  __shared__ int s[256], ofs[256], cur[256];
  int t = threadIdx.x;
  int tv = bucketTot[t];
  s[t] = tv; __syncthreads();
  for (int off=1; off<256; off<<=1){
    int u = (t>=off) ? s[t-off] : 0;
    __syncthreads();
    s[t] += u;
    __syncthreads();
  }
  ofs[t] = (s[t] - tv) + blockOfs[t*A_BLOCKS + blockIdx.x];
  cur[t] = 0;
  __syncthreads();
  int base = blockIdx.x * EDGES_PER_A;
  for (int i = t; i < EDGES_PER_A; i += 256){
    int d = dst[base+i];
    int b = d >> 8;
    int p = atomicAdd(&cur[b], 1);
    binned[ofs[b] + p] = (unsigned)(src[base+i] & 0xFFFF) | ((unsigned)(d & 0xFF) << 16);
  }
}

// ---------- binning B: CSR finalize + SLICED xs0 epilogue ----------
__global__ __launch_bounds__(256) void k_binFinal(const unsigned* __restrict__ binned,
                         const int* __restrict__ bucketTot, const int* __restrict__ feat,
                         const __half* __restrict__ embh,
                         unsigned short* __restrict__ eSrc, __half* __restrict__ xs0,
                         int* __restrict__ rowStart, int* __restrict__ deg, float* __restrict__ dinv){
  __shared__ int h[256], pre[256], cur[256], excl[256];
  __shared__ float dinvS[256];
  __shared__ unsigned short sE[SE_CAP];
  int b = blockIdx.x;
  int t = threadIdx.x;
  int tv = bucketTot[t];
  pre[t] = tv; __syncthreads();
  for (int off=1; off<256; off<<=1){
    int u = (t>=off) ? pre[t-off] : 0;
    __syncthreads();
    pre[t] += u;
    __syncthreads();
  }
  excl[t] = pre[t] - tv;
  __syncthreads();
  int base = excl[b], cnt = bucketTot[b];
  int nodeBase = b << 8;
  h[t] = 0; __syncthreads();
  for (int i = t; i < cnt; i += 256)
    atomicAdd(&h[binned[base+i] >> 16], 1);
  __syncthreads();
  pre[t] = h[t]; __syncthreads();
  for (int off=1; off<256; off<<=1){
    int u = (t>=off) ? pre[t-off] : 0;
    __syncthreads();
    pre[t] += u;
    __syncthreads();
  }
  int node = nodeBase + t;
  float dn = 0.f;
  if (node < N_NODES){
    int d = h[t];
    deg[node] = d;
    rowStart[node] = base + pre[t] - d;
    dn = rsqrtf((float)d + 1.0f);
    dinv[node] = dn;
  }
  dinvS[t] = dn;
  cur[t] = pre[t] - h[t];
  __syncthreads();
  for (int i = t; i < cnt; i += 256){
    unsigned v = binned[base+i];
    int dl = v >> 16;
    int p = atomicAdd(&cur[dl], 1);
    unsigned short s = (unsigned short)(v & 0xFFFF);
    if (p < SE_CAP) sE[p] = s;
    else eSrc[base + p] = s;
  }
  __syncthreads();
  int lim = cnt < SE_CAP ? cnt : SE_CAP;
  for (int i = t; i < lim; i += 256) eSrc[base+i] = sE[i];
  // xs0 epilogue (sliced layout): chunk l16 -> slice l16>>1, half l16&1
  int l16 = t & 15;
  for (int n = t >> 4; n < 256; n += 16){
    int nd = nodeBase + n;
    if (nd < N_NODES){
      short8v v = ((const short8v*)embh)[(size_t)feat[nd]*16 + l16];
      float d = dinvS[n];
      short8v o;
      #pragma unroll
      for (int i=0;i<8;i++)
        o[i] = (short)__builtin_bit_cast(unsigned short, __float2half(d * h2f(v[i])));
      ((short8v*)xs0)[(size_t)(l16>>1)*((size_t)N_NODES*2) + (size_t)nd*2 + (l16&1)] = o;
    }
  }
}

// ---------- sliced aggregation: slice = blockIdx&7 (XCD-affine), 2 lanes per node ----------
// u[node][slice ch] = split_bf16( dinv_node * ( gsrc_sl[slice][node] + sum gsrc_sl[slice][eSrc] ) )

__global__ __launch_bounds__(256) void k_aggSl(const __half* __restrict__ gsrc_sl,
                      const unsigned short* __restrict__ eSrc,
                      const int* __restrict__ rowStart, const int* __restrict__ deg,
                      const float* __restrict__ dinv,
                      unsigned short* __restrict__ uh, unsigned short* __restrict__ ul){
  int t = threadIdx.x;
  int slice = blockIdx.x & 7;
  int tile  = blockIdx.x >> 3;
  int half  = t & 1;                    // 8-ch half of the 16-ch slice
  int node  = tile*128 + (t >> 1);
  if (node >= N_NODES) return;
  const short8v* X = (const short8v*)gsrc_sl + (size_t)slice*((size_t)N_NODES*2);
  float a[8];
  {
    short8v sv = X[(size_t)node*2 + half];
    #pragma unroll
    for (int i=0;i<8;i++) a[i] = h2f(sv[i]);
  }
  int rs = rowStart[node], len = deg[node];
  int k = 0;
  for (; k+8<=len; k+=8){
    int s[8];
    #pragma unroll
    for (int j=0;j<8;j++) s[j] = eSrc[rs+k+j];
    short8v v[8];
    #pragma unroll
    for (int j=0;j<8;j++) v[j] = X[(size_t)s[j]*2 + half];
    #pragma unroll
    for (int j=0;j<8;j++)
      #pragma unroll
      for (int i=0;i<8;i++) a[i] += h2f(v[j][i]);
  }
  int rem = len - k;
  if (rem > 0){
    int sR[7]; short8v vR[7];
    #pragma unroll
    for (int j=0;j<7;j++) sR[j] = (j < rem) ? (int)eSrc[rs+k+j] : node;
    #pragma unroll
    for (int j=0;j<7;j++) vR[j] = X[(size_t)sR[j]*2 + half];
    #pragma unroll
    for (int j=0;j<7;j++){
      if (j < rem){
        #pragma unroll
        for (int i=0;i<8;i++) a[i] += h2f(vR[j][i]);
      }
    }
  }
  float dn = dinv[node];
  short8v hv, lv;
  #pragma unroll
  for (int i=0;i<8;i++){
    float f = a[i] * dn;
    unsigned short hh = f2bf(f);
    hv[i] = (short)hh;
    lv[i] = (short)f2bf(f - bf2f(hh));
  }
  size_t uidx = (size_t)node*16 + slice*2 + half;   // node-major planes
  ((short8v*)uh)[uidx] = hv;
  ((short8v*)ul)[uidx] = lv;
}

// ---------- gemm layers 1-2: xs_sl = fp16( dinv * relu(u@W + b) ), sliced output ----------

__global__ __launch_bounds__(256) void k_gemmA(
            const unsigned short* __restrict__ uh, const unsigned short* __restrict__ ul,
            const short* __restrict__ Bh, const short* __restrict__ Bl,
            const float* __restrict__ bias, const float* __restrict__ dinv,
            __half* __restrict__ xsOut){
  int lane = threadIdx.x & 63;
  int pb = blockIdx.x*4 + (threadIdx.x >> 6);
  int R0 = pb*16;
  if (R0 >= N_NODES) return;
  int r15 = lane & 15, q = lane >> 4;
  int row = R0 + r15;
  const short8v* AH = (const short8v*)(uh + (size_t)row*C);
  const short8v* AL = (const short8v*)(ul + (size_t)row*C);
  const short8v* BH = (const short8v*)Bh;
  const short8v* BL = (const short8v*)Bl;
  f32x4 acc[8];
  #pragma unroll
  for (int ct=0;ct<8;ct++) acc[ct] = (f32x4){0.f,0.f,0.f,0.f};
  #pragma unroll
  for (int kt=0; kt<4; kt++){
    short8v ah = AH[kt*4 + q];
    short8v al = AL[kt*4 + q];
    #pragma unroll
    for (int ct=0; ct<8; ct++){
      short8v bh = BH[(kt*8+ct)*64 + lane];
      short8v bl = BL[(kt*8+ct)*64 + lane];
      acc[ct] = __builtin_amdgcn_mfma_f32_16x16x32_bf16(ah, bh, acc[ct], 0, 0, 0);
      acc[ct] = __builtin_amdgcn_mfma_f32_16x16x32_bf16(al, bh, acc[ct], 0, 0, 0);
      acc[ct] = __builtin_amdgcn_mfma_f32_16x16x32_bf16(ah, bl, acc[ct], 0, 0, 0);
    }
  }
  float bb[8];
  #pragma unroll
  for (int ct=0;ct<8;ct++) bb[ct] = bias[ct*16 + r15];
  #pragma unroll
  for (int j=0;j<4;j++){
    int rz = R0 + q*4 + j;
    float d = dinv[rz];
    #pragma unroll
    for (int ct=0; ct<8; ct++){
      float v = fmaxf(acc[ct][j] + bb[ct], 0.f);
      // channel = ct*16 + r15 -> slice ct, within-slice ch r15
      xsOut[(size_t)ct*SLICE_H + (size_t)rz*16 + r15] = __float2half(v * d);
    }
  }
}

// ---------- gemm layer 3: dots[i] = relu(u@W3 + b3) . fcW ----------

__global__ __launch_bounds__(256) void k_gemm3(
            const unsigned short* __restrict__ uh, const unsigned short* __restrict__ ul,
            const short* __restrict__ Bh, const short* __restrict__ Bl,
            const float* __restrict__ bias, const float* __restrict__ fcW,
            float* __restrict__ dots){
  int lane = threadIdx.x & 63;
  int pb = blockIdx.x*4 + (threadIdx.x >> 6);
  int R0 = pb*16;
  if (R0 >= N_NODES) return;
  int r15 = lane & 15, q = lane >> 4;
  int row = R0 + r15;
  const short8v* AH = (const short8v*)(uh + (size_t)row*C);
  const short8v* AL = (const short8v*)(ul + (size_t)row*C);
  const short8v* BH = (const short8v*)Bh;
  const short8v* BL = (const short8v*)Bl;
  f32x4 acc[8];
  #pragma unroll
  for (int ct=0;ct<8;ct++) acc[ct] = (f32x4){0.f,0.f,0.f,0.f};
  #pragma unroll
  for (int kt=0; kt<4; kt++){
    short8v ah = AH[kt*4 + q];
    short8v al = AL[kt*4 + q];
    #pragma unroll
    for (int ct=0; ct<8; ct++){
      short8v bh = BH[(kt*8+ct)*64 + lane];
      short8v bl = BL[(kt*8+ct)*64 + lane];
      acc[ct] = __builtin_amdgcn_mfma_f32_16x16x32_bf16(ah, bh, acc[ct], 0, 0, 0);
      acc[ct] = __builtin_amdgcn_mfma_f32_16x16x32_bf16(al, bh, acc[ct], 0, 0, 0);
      acc[ct] = __builtin_amdgcn_mfma_f32_16x16x32_bf16(ah, bl, acc[ct], 0, 0, 0);
    }
  }
  float bb[8], fw[8];
  #pragma unroll
  for (int ct=0;ct<8;ct++){ bb[ct] = bias[ct*16 + r15]; fw[ct] = fcW[ct*16 + r15]; }
  #pragma unroll
  for (int j=0;j<4;j++){
    int rz = R0 + q*4 + j;
    float s = 0.f;
    #pragma unroll
    for (int ct=0; ct<8; ct++)
      s += fmaxf(acc[ct][j] + bb[ct], 0.f) * fw[ct];
    s += __shfl_xor(s, 1);
    s += __shfl_xor(s, 2);
    s += __shfl_xor(s, 4);
    s += __shfl_xor(s, 8);
    if (r15 == 0) dots[rz] = s;
  }
}

// ---------- pooling ----------

__global__ void k_pool_seg(const float* __restrict__ dots, const int* __restrict__ gStart,
                           const float* __restrict__ fcb, float* __restrict__ out){
  __shared__ float s[256];
  int g = blockIdx.x;
  int st = gStart[g], en = gStart[g+1];
  float acc = 0.f;
  for (int i = st + threadIdx.x; i < en; i += 256) acc += dots[i];
  s[threadIdx.x] = acc; __syncthreads();
  for (int off=128; off>0; off>>=1){
    if (threadIdx.x < off) s[threadIdx.x] += s[threadIdx.x+off];
    __syncthreads();
  }
  if (threadIdx.x==0) out[g] = s[0]/fmaxf((float)(en-st),1.0f) + fcb[0];
}

// ---------- launch ----------

extern "C" void kernel_launch(void* const* d_in, const int* in_sizes, int n_in,
                              void* d_out, int out_size, void* d_ws, size_t ws_size,
                              hipStream_t stream){
  const int* edge  = (const int*)d_in[0];
  const int* srcI  = edge;
  const int* dstI  = edge + N_EDGES;
  const int* feat  = (const int*)d_in[1];
  const int* batch = (const int*)d_in[2];
  const float* emb = (const float*)d_in[3];
  const float* W1  = (const float*)d_in[4];
  const float* b1  = (const float*)d_in[5];
  const float* W2  = (const float*)d_in[6];
  const float* b2  = (const float*)d_in[7];
  const float* W3  = (const float*)d_in[8];
  const float* b3  = (const float*)d_in[9];
  const float* fcW = (const float*)d_in[10];
  const float* fcb = (const float*)d_in[11];
  float* out = (float*)d_out;

  __half* xsA = (__half*)d_ws;                       // sliced N*C f16
  __half* xsB = xsA + (size_t)N_NODES*C;             // sliced N*C f16
  __half* xs0 = xsB + (size_t)N_NODES*C;             // sliced N*C f16
  unsigned short* uhp = (unsigned short*)(xs0 + (size_t)N_NODES*C);  // node-major N*C
  unsigned short* ulp = uhp + (size_t)N_NODES*C;     // node-major N*C
  __half* embh = (__half*)(ulp + (size_t)N_NODES*C); // VOCAB*C f16
  unsigned* binned = (unsigned*)(embh + (size_t)VOCAB*C); // 800000 u32
  unsigned short* eSrc  = (unsigned short*)(binned + N_EDGES);  // 800000 u16
  int* rowStart = (int*)(eSrc + N_EDGES);            // 50000
  int* deg      = rowStart + N_NODES;                // 50000
  float* dinv   = (float*)(deg + N_NODES);           // 50000
  int* blockHist = (int*)(dinv + N_NODES);           // 256*200
  int* blockOfs  = blockHist + 256*A_BLOCKS;         // 256*200
  int* bucketTot = blockOfs + 256*A_BLOCKS;          // 256
  int* gStart    = bucketTot + 256;                  // 513 (+pad)
  float* dots   = (float*)(gStart + 520);            // 50000
  short* Bpack  = (short*)(dots + N_NODES);          // 6*16384 shorts
  short* Bh1 = Bpack,           * Bl1 = Bpack + 16384;
  short* Bh2 = Bpack + 2*16384, * Bl2 = Bpack + 3*16384;
  short* Bh3 = Bpack + 4*16384, * Bl3 = Bpack + 5*16384;

  k_pre       <<<A_BLOCKS+NBUCK+24+64, 256, 0, stream>>>(dstI, blockHist, batch, gStart,
                                                         W1, W2, W3, Bpack, emb, embh);
  k_binScanA  <<<256, 64, 0, stream>>>(blockHist, blockOfs, bucketTot);
  k_binScatter<<<A_BLOCKS, 256, 0, stream>>>(srcI, dstI, bucketTot, blockOfs, binned);
  k_binFinal  <<<NBUCK, 256, 0, stream>>>(binned, bucketTot, feat, embh, eSrc, xs0,
                                          rowStart, deg, dinv);

  int aggBlocks  = NSLICE * ((N_NODES + 127)/128);   // 8 * 391 = 3128
  int gemmBlocks = (N_NODES/16 + 3)/4;               // 782
  // layer 1
  k_aggSl<<<aggBlocks, 256, 0, stream>>>(xs0, eSrc, rowStart, deg, dinv, uhp, ulp);
  k_gemmA<<<gemmBlocks, 256, 0, stream>>>(uhp, ulp, Bh1, Bl1, b1, dinv, xsB);
  // layer 2
  k_aggSl<<<aggBlocks, 256, 0, stream>>>(xsB, eSrc, rowStart, deg, dinv, uhp, ulp);
  k_gemmA<<<gemmBlocks, 256, 0, stream>>>(uhp, ulp, Bh2, Bl2, b2, dinv, xsA);
  // layer 3
  k_aggSl<<<aggBlocks, 256, 0, stream>>>(xsA, eSrc, rowStart, deg, dinv, uhp, ulp);
  k_gemm3<<<gemmBlocks, 256, 0, stream>>>(uhp, ulp, Bh3, Bl3, b3, fcW, dots);

  k_pool_seg<<<N_GRAPHS, 256, 0, stream>>>(dots, gStart, fcb, out);
}

// Round 18
// 166.571 us; speedup vs baseline: 1.3053x; 1.3053x over previous
//
#include <hip/hip_runtime.h>
#include <hip/hip_fp16.h>

#define N_NODES 50000
#define N_EDGES 800000
#define N_GRAPHS 512
#define VOCAB 10000
#define C 128
#define NBUCK 196            // ceil(50000/256), bucket = dst>>8
#define A_BLOCKS 200         // 4000 edges each
#define EDGES_PER_A (N_EDGES / A_BLOCKS)
#define SE_CAP 8192          // LDS eSrc staging per bucket (mean 4096)

typedef __attribute__((ext_vector_type(8))) short short8v;
typedef __attribute__((ext_vector_type(4))) float f32x4;

__device__ __forceinline__ unsigned short f2bf(float f){
  unsigned u = __builtin_bit_cast(unsigned, f);
  unsigned r = u + 0x7FFFu + ((u >> 16) & 1u);
  return (unsigned short)(r >> 16);
}
__device__ __forceinline__ float bf2f(unsigned short h){
  unsigned u = ((unsigned)h) << 16;
  return __builtin_bit_cast(float, u);
}
__device__ __forceinline__ float h2f(short s){
  return __half2float(__builtin_bit_cast(__half, (unsigned short)s));
}

// ---------- K1: binCount (200) | gstart (196) | W-prepack (24) | emb->fp16 (64) ----------
__global__ __launch_bounds__(256) void k_pre(const int* __restrict__ dst, int* __restrict__ blockHist,
                      const int* __restrict__ batch, int* __restrict__ gStart,
                      const float* __restrict__ W1, const float* __restrict__ W2,
                      const float* __restrict__ W3, short* __restrict__ Bp,
                      const float* __restrict__ emb, __half* __restrict__ embh){
  __shared__ int h[256];
  int b = blockIdx.x, t = threadIdx.x;
  if (b < A_BLOCKS){                    // binCount (bucket-major store)
    h[t] = 0; __syncthreads();
    int base = b * EDGES_PER_A;
    for (int i = t; i < EDGES_PER_A; i += 256)
      atomicAdd(&h[dst[base+i] >> 8], 1);
    __syncthreads();
    blockHist[t*A_BLOCKS + b] = h[t];
  } else if (b < A_BLOCKS+NBUCK){       // gstart
    int i = (b-A_BLOCKS)*256 + t;
    if (i >= N_NODES) return;
    int bb = batch[i];
    int pb = (i==0) ? -1 : batch[i-1];
    for (int g=pb+1; g<=bb; g++) gStart[g] = i;
    if (i == N_NODES-1)
      for (int g=bb+1; g<=N_GRAPHS; g++) gStart[g] = N_NODES;
  } else if (b < A_BLOCKS+NBUCK+24){    // W prepack (3 layers x 2048 threads)
    int idx = (b-A_BLOCKS-NBUCK)*256 + t;  // 0..6143
    int layer = idx / 2048;
    int r = idx - layer*2048;
    const float* W = (layer==0) ? W1 : (layer==1) ? W2 : W3;
    short* Bh = Bp + (size_t)layer*32768;
    short* Bl = Bh + 16384;
    int lane = r & 63, tile = r >> 6;   // tile = kt*8 + ct
    int kt = tile >> 3, ct = tile & 7;
    int q = lane >> 4, c = ct*16 + (lane & 15);
    #pragma unroll
    for (int i=0;i<8;i++){
      int k = kt*32 + q*8 + i;
      float w = W[k*C + c];
      unsigned short hh = f2bf(w);
      unsigned short ll = f2bf(w - bf2f(hh));
      Bh[(size_t)(tile*64 + lane)*8 + i] = (short)hh;
      Bl[(size_t)(tile*64 + lane)*8 + i] = (short)ll;
    }
  } else {                              // emb -> fp16 (64 blocks)
    int idx = (b-A_BLOCKS-NBUCK-24)*256 + t;
    const float2* s = (const float2*)emb;
    __half2* d2 = (__half2*)embh;
    for (int i = idx; i < VOCAB*C/2; i += 64*256)
      d2[i] = __float22half2_rn(s[i]);
  }
}

// ---------- scan A: wave per bucket, prefix over 200 block entries ----------
__global__ __launch_bounds__(64) void k_binScanA(const int* __restrict__ blockHist,
                        int* __restrict__ blockOfs, int* __restrict__ bucketTot){
  int b = blockIdx.x;
  int l = threadIdx.x;
  int carry = 0;
  for (int c = 0; c < 256; c += 64){
    int idx = c + l;
    int v = (idx < A_BLOCKS) ? blockHist[b*A_BLOCKS + idx] : 0;
    int x = v;
    #pragma unroll
    for (int off=1; off<64; off<<=1){
      int y = __shfl_up(x, off);
      if (l >= off) x += y;
    }
    if (idx < A_BLOCKS) blockOfs[b*A_BLOCKS + idx] = carry + x - v;
    carry += __shfl(x, 63);
  }
  if (l == 0) bucketTot[b] = carry;
}

// ---------- binning A2: scatter packed edges (bucket bases scanned in-block) ----------
__global__ __launch_bounds__(256) void k_binScatter(const int* __restrict__ src, const int* __restrict__ dst,
                           const int* __restrict__ bucketTot, const int* __restrict__ blockOfs,
                           unsigned* __restrict__ binned){
  __shared__ int s[256], ofs[256], cur[256];
  int t = threadIdx.x;
  int tv = bucketTot[t];
  s[t] = tv; __syncthreads();
  for (int off=1; off<256; off<<=1){
    int u = (t>=off) ? s[t-off] : 0;
    __syncthreads();
    s[t] += u;
    __syncthreads();
  }
  ofs[t] = (s[t] - tv) + blockOfs[t*A_BLOCKS + blockIdx.x];
  cur[t] = 0;
  __syncthreads();
  int base = blockIdx.x * EDGES_PER_A;
  for (int i = t; i < EDGES_PER_A; i += 256){
    int d = dst[base+i];
    int b = d >> 8;
    int p = atomicAdd(&cur[b], 1);
    binned[ofs[b] + p] = (unsigned)(src[base+i] & 0xFFFF) | ((unsigned)(d & 0xFF) << 16);
  }
}

// ---------- binning B: CSR finalize + xs0 epilogue (xs0[n] = fp16(dinv_n * emb[feat_n])) ----------
__global__ __launch_bounds__(256) void k_binFinal(const unsigned* __restrict__ binned,
                         const int* __restrict__ bucketTot, const int* __restrict__ feat,
                         const __half* __restrict__ embh,
                         unsigned short* __restrict__ eSrc, __half* __restrict__ xs0,
                         int* __restrict__ rowStart, int* __restrict__ deg, float* __restrict__ dinv){
  __shared__ int h[256], pre[256], cur[256], excl[256];
  __shared__ float dinvS[256];
  __shared__ unsigned short sE[SE_CAP];
  int b = blockIdx.x;
  int t = threadIdx.x;
  int tv = bucketTot[t];
  pre[t] = tv; __syncthreads();
  for (int off=1; off<256; off<<=1){
    int u = (t>=off) ? pre[t-off] : 0;
    __syncthreads();
    pre[t] += u;
    __syncthreads();
  }
  excl[t] = pre[t] - tv;
  __syncthreads();
  int base = excl[b], cnt = bucketTot[b];
  int nodeBase = b << 8;
  h[t] = 0; __syncthreads();
  for (int i = t; i < cnt; i += 256)
    atomicAdd(&h[binned[base+i] >> 16], 1);
  __syncthreads();
  pre[t] = h[t]; __syncthreads();
  for (int off=1; off<256; off<<=1){
    int u = (t>=off) ? pre[t-off] : 0;
    __syncthreads();
    pre[t] += u;
    __syncthreads();
  }
  int node = nodeBase + t;
  float dn = 0.f;
  if (node < N_NODES){
    int d = h[t];
    deg[node] = d;
    rowStart[node] = base + pre[t] - d;
    dn = rsqrtf((float)d + 1.0f);
    dinv[node] = dn;
  }
  dinvS[t] = dn;
  cur[t] = pre[t] - h[t];
  __syncthreads();
  for (int i = t; i < cnt; i += 256){
    unsigned v = binned[base+i];
    int dl = v >> 16;
    int p = atomicAdd(&cur[dl], 1);
    unsigned short s = (unsigned short)(v & 0xFFFF);
    if (p < SE_CAP) sE[p] = s;
    else eSrc[base + p] = s;
  }
  __syncthreads();
  int lim = cnt < SE_CAP ? cnt : SE_CAP;
  for (int i = t; i < lim; i += 256) eSrc[base+i] = sE[i];
  // xs0 epilogue: 16 threads per node, 16 nodes per pass
  int l16 = t & 15;
  for (int n = t >> 4; n < 256; n += 16){
    int nd = nodeBase + n;
    if (nd < N_NODES){
      short8v v = ((const short8v*)embh)[(size_t)feat[nd]*16 + l16];
      float d = dinvS[n];
      short8v o;
      #pragma unroll
      for (int i=0;i<8;i++)
        o[i] = (short)__builtin_bit_cast(unsigned short, __float2half(d * h2f(v[i])));
      ((short8v*)xs0)[(size_t)nd*16 + l16] = o;
    }
  }
}

// ---------- fused layer: pipelined gather -> LDS u-tile -> MFMA ----------
// block = 16 nodes = 1 row-tile; quarter-wave per node; gather 3-stage pipelined.
// u = dinv_node * (gsrc[node] + sum gsrc[eSrc]); LAYER<3: xs=fp16(dinv*relu(u@W+b)); 3: dots.

template<int LAYER>
__global__ __launch_bounds__(256, 4) void k_layer(
      const __half* __restrict__ gsrc,
      const unsigned short* __restrict__ eSrc,
      const int* __restrict__ rowStart, const int* __restrict__ deg,
      const float* __restrict__ dinv,
      const short* __restrict__ Bh, const short* __restrict__ Bl,
      const float* __restrict__ bias, const float* __restrict__ fcW,
      __half* __restrict__ xsOut, float* __restrict__ dots){
  __shared__ unsigned short uhl[16*C];
  __shared__ unsigned short ull[16*C];
  __shared__ float dotb[16][4];
  int t = threadIdx.x;
  int wave = t>>6, lane = t&63;
  int sub = lane>>4, l16 = lane&15;
  int node0 = blockIdx.x*16;
  int r = wave*4 + sub;
  int node = node0 + r;

  float a[8];
  {
    int rs = rowStart[node], len = deg[node];
    float dn = dinv[node];
    const short8v* X = (const short8v*)gsrc;
    short8v sv = X[(size_t)node*16 + l16];
    #pragma unroll
    for (int i=0;i<8;i++) a[i] = h2f(sv[i]);

    int nb = len >> 3;
    int k = nb << 3;
    if (nb >= 2){
      int iA[8], iB[8];
      short8v rA[8], rB[8];
      #pragma unroll
      for (int j=0;j<8;j++) iA[j] = eSrc[rs+j];
      #pragma unroll
      for (int j=0;j<8;j++) iB[j] = eSrc[rs+8+j];
      #pragma unroll
      for (int j=0;j<8;j++) rA[j] = X[(size_t)iA[j]*16 + l16];
      for (int c=2; c<nb; c++){
        int iC[8];
        #pragma unroll
        for (int j=0;j<8;j++) iC[j] = eSrc[rs + c*8 + j];
        #pragma unroll
        for (int j=0;j<8;j++) rB[j] = X[(size_t)iB[j]*16 + l16];
        #pragma unroll
        for (int j=0;j<8;j++)
          #pragma unroll
          for (int i=0;i<8;i++) a[i] += h2f(rA[j][i]);
        #pragma unroll
        for (int j=0;j<8;j++){ rA[j]=rB[j]; iB[j]=iC[j]; }
      }
      #pragma unroll
      for (int j=0;j<8;j++) rB[j] = X[(size_t)iB[j]*16 + l16];
      #pragma unroll
      for (int j=0;j<8;j++)
        #pragma unroll
        for (int i=0;i<8;i++) a[i] += h2f(rA[j][i]);
      #pragma unroll
      for (int j=0;j<8;j++)
        #pragma unroll
        for (int i=0;i<8;i++) a[i] += h2f(rB[j][i]);
    } else if (nb == 1){
      int s1[8]; short8v v1[8];
      #pragma unroll
      for (int j=0;j<8;j++) s1[j] = eSrc[rs+j];
      #pragma unroll
      for (int j=0;j<8;j++) v1[j] = X[(size_t)s1[j]*16 + l16];
      #pragma unroll
      for (int j=0;j<8;j++)
        #pragma unroll
        for (int i=0;i<8;i++) a[i] += h2f(v1[j][i]);
    }
    int rem = len - k;
    if (rem > 0){
      int sR[7]; short8v vR[7];
      #pragma unroll
      for (int j=0;j<7;j++) sR[j] = (j < rem) ? (int)eSrc[rs+k+j] : node;
      #pragma unroll
      for (int j=0;j<7;j++) vR[j] = X[(size_t)sR[j]*16 + l16];
      #pragma unroll
      for (int j=0;j<7;j++){
        if (j < rem){
          #pragma unroll
          for (int i=0;i<8;i++) a[i] += h2f(vR[j][i]);
        }
      }
    }
    #pragma unroll
    for (int i=0;i<8;i++) a[i] *= dn;
  }
  // split-bf16 store to LDS (16B-granularity XOR swizzle)
  {
    short8v hv, lv;
    #pragma unroll
    for (int i=0;i<8;i++){
      unsigned short hh = f2bf(a[i]);
      hv[i] = (short)hh;
      lv[i] = (short)f2bf(a[i] - bf2f(hh));
    }
    unsigned boff = (unsigned)(r*256 + l16*16) ^ ((unsigned)(r&7)<<4);
    *(short8v*)((char*)uhl + boff) = hv;
    *(short8v*)((char*)ull + boff) = lv;
  }
  __syncthreads();

  // ---- GEMM phase: wave owns column-tiles ct = 2*wave, 2*wave+1 ----
  int r15 = lane & 15, q = lane >> 4;
  const short8v* BH = (const short8v*)Bh;
  const short8v* BL = (const short8v*)Bl;
  f32x4 acc[2];
  acc[0] = (f32x4){0.f,0.f,0.f,0.f};
  acc[1] = (f32x4){0.f,0.f,0.f,0.f};
  #pragma unroll
  for (int kt=0; kt<4; kt++){
    unsigned boff = (unsigned)(r15*256 + (kt*4+q)*16) ^ ((unsigned)(r15&7)<<4);
    short8v ah = *(const short8v*)((const char*)uhl + boff);
    short8v al = *(const short8v*)((const char*)ull + boff);
    #pragma unroll
    for (int c=0;c<2;c++){
      int ct = wave*2 + c;
      short8v bh = BH[(kt*8+ct)*64 + lane];
      short8v bl = BL[(kt*8+ct)*64 + lane];
      acc[c] = __builtin_amdgcn_mfma_f32_16x16x32_bf16(ah, bh, acc[c], 0, 0, 0);
      acc[c] = __builtin_amdgcn_mfma_f32_16x16x32_bf16(al, bh, acc[c], 0, 0, 0);
      acc[c] = __builtin_amdgcn_mfma_f32_16x16x32_bf16(ah, bl, acc[c], 0, 0, 0);
    }
  }
  float bb[2] = { bias[(wave*2)*16 + r15], bias[(wave*2+1)*16 + r15] };
  if (LAYER == 3){
    float fw[2] = { fcW[(wave*2)*16 + r15], fcW[(wave*2+1)*16 + r15] };
    #pragma unroll
    for (int j=0;j<4;j++){
      float s = fmaxf(acc[0][j] + bb[0], 0.f)*fw[0]
              + fmaxf(acc[1][j] + bb[1], 0.f)*fw[1];
      s += __shfl_xor(s, 1);
      s += __shfl_xor(s, 2);
      s += __shfl_xor(s, 4);
      s += __shfl_xor(s, 8);
      if (r15 == 0) dotb[q*4 + j][wave] = s;
    }
    __syncthreads();
    if (t < 16) dots[node0 + t] = dotb[t][0] + dotb[t][1] + dotb[t][2] + dotb[t][3];
  } else {
    #pragma unroll
    for (int j=0;j<4;j++){
      int rz = node0 + q*4 + j;
      float d = dinv[rz];
      #pragma unroll
      for (int c=0;c<2;c++){
        float v = fmaxf(acc[c][j] + bb[c], 0.f);
        xsOut[(size_t)rz*C + (wave*2+c)*16 + r15] = __float2half(v * d);
      }
    }
  }
}

// ---------- pooling ----------

__global__ void k_pool_seg(const float* __restrict__ dots, const int* __restrict__ gStart,
                           const float* __restrict__ fcb, float* __restrict__ out){
  __shared__ float s[256];
  int g = blockIdx.x;
  int st = gStart[g], en = gStart[g+1];
  float acc = 0.f;
  for (int i = st + threadIdx.x; i < en; i += 256) acc += dots[i];
  s[threadIdx.x] = acc; __syncthreads();
  for (int off=128; off>0; off>>=1){
    if (threadIdx.x < off) s[threadIdx.x] += s[threadIdx.x+off];
    __syncthreads();
  }
  if (threadIdx.x==0) out[g] = s[0]/fmaxf((float)(en-st),1.0f) + fcb[0];
}

// ---------- launch ----------

extern "C" void kernel_launch(void* const* d_in, const int* in_sizes, int n_in,
                              void* d_out, int out_size, void* d_ws, size_t ws_size,
                              hipStream_t stream){
  const int* edge  = (const int*)d_in[0];
  const int* srcI  = edge;
  const int* dstI  = edge + N_EDGES;
  const int* feat  = (const int*)d_in[1];
  const int* batch = (const int*)d_in[2];
  const float* emb = (const float*)d_in[3];
  const float* W1  = (const float*)d_in[4];
  const float* b1  = (const float*)d_in[5];
  const float* W2  = (const float*)d_in[6];
  const float* b2  = (const float*)d_in[7];
  const float* W3  = (const float*)d_in[8];
  const float* b3  = (const float*)d_in[9];
  const float* fcW = (const float*)d_in[10];
  const float* fcb = (const float*)d_in[11];
  float* out = (float*)d_out;

  __half* xsA = (__half*)d_ws;                       // N*C f16
  __half* xsB = xsA + (size_t)N_NODES*C;             // N*C f16
  __half* xs0 = xsB + (size_t)N_NODES*C;             // N*C f16
  __half* embh = xs0 + (size_t)N_NODES*C;            // VOCAB*C f16
  unsigned* binned = (unsigned*)(embh + (size_t)VOCAB*C); // 800000 u32
  unsigned short* eSrc  = (unsigned short*)(binned + N_EDGES);  // 800000 u16
  int* rowStart = (int*)(eSrc + N_EDGES);            // 50000
  int* deg      = rowStart + N_NODES;                // 50000
  float* dinv   = (float*)(deg + N_NODES);           // 50000
  int* blockHist = (int*)(dinv + N_NODES);           // 256*200
  int* blockOfs  = blockHist + 256*A_BLOCKS;         // 256*200
  int* bucketTot = blockOfs + 256*A_BLOCKS;          // 256
  int* gStart    = bucketTot + 256;                  // 513 (+pad)
  float* dots   = (float*)(gStart + 520);            // 50000
  short* Bpack  = (short*)(dots + N_NODES);          // 6*16384 shorts
  short* Bh1 = Bpack,           * Bl1 = Bpack + 16384;
  short* Bh2 = Bpack + 2*16384, * Bl2 = Bpack + 3*16384;
  short* Bh3 = Bpack + 4*16384, * Bl3 = Bpack + 5*16384;

  k_pre       <<<A_BLOCKS+NBUCK+24+64, 256, 0, stream>>>(dstI, blockHist, batch, gStart,
                                                         W1, W2, W3, Bpack, emb, embh);
  k_binScanA  <<<256, 64, 0, stream>>>(blockHist, blockOfs, bucketTot);
  k_binScatter<<<A_BLOCKS, 256, 0, stream>>>(srcI, dstI, bucketTot, blockOfs, binned);
  k_binFinal  <<<NBUCK, 256, 0, stream>>>(binned, bucketTot, feat, embh, eSrc, xs0,
                                          rowStart, deg, dinv);

  int LBLOCKS = N_NODES/16;   // 3125 exactly
  k_layer<1><<<LBLOCKS, 256, 0, stream>>>(xs0, eSrc, rowStart, deg, dinv,
                                          Bh1, Bl1, b1, nullptr, xsB, nullptr);
  k_layer<2><<<LBLOCKS, 256, 0, stream>>>(xsB, eSrc, rowStart, deg, dinv,
                                          Bh2, Bl2, b2, nullptr, xsA, nullptr);
  k_layer<3><<<LBLOCKS, 256, 0, stream>>>(xsA, eSrc, rowStart, deg, dinv,
                                          Bh3, Bl3, b3, fcW, nullptr, dots);

  k_pool_seg<<<N_GRAPHS, 256, 0, stream>>>(dots, gStart, fcb, out);
}